// Round 2
// baseline (483.523 us; speedup 1.0000x reference)
//
#include <hip/hip_runtime.h>
#include <cstdint>
#include <cstddef>

typedef __bf16 bf16_t;
typedef __bf16 bf16x8 __attribute__((ext_vector_type(8)));
typedef __bf16 bf16x4 __attribute__((ext_vector_type(4)));
typedef float  f32x4  __attribute__((ext_vector_type(4)));

#define MFMA16(a, b, c) __builtin_amdgcn_mfma_f32_16x16x32_bf16((a), (b), (c), 0, 0, 0)

// async global->LDS, 16B per lane. LDS dest must be wave-linear (base + lane*16).
__device__ __forceinline__ void gload_lds16(const bf16_t* g, bf16_t* l) {
  __builtin_amdgcn_global_load_lds(
      (__attribute__((address_space(1))) void*)((void*)g),
      (__attribute__((address_space(3))) void*)l, 16, 0, 0);
}

// ---------------------------------------------------------------------------
// x convert: f32 -> bf16, 4 elems/thread.
// ---------------------------------------------------------------------------
__global__ __launch_bounds__(256) void cvt_f32_bf16(
    const float* __restrict__ in, bf16_t* __restrict__ out, int n) {
  const int i = (blockIdx.x * 256 + threadIdx.x) * 4;
  if (i + 3 < n) {
    const float4 v = *(const float4*)(in + i);
    bf16x4 o;
    o[0] = (bf16_t)v.x; o[1] = (bf16_t)v.y; o[2] = (bf16_t)v.z; o[3] = (bf16_t)v.w;
    *(bf16x4*)(out + i) = o;
  }
}

// ---------------------------------------------------------------------------
// Weight transpose+convert: in f32 [R][C] -> out bf16 [C][R]; R,C mult of 32.
// ---------------------------------------------------------------------------
__global__ __launch_bounds__(256) void transpose_f32_bf16(
    const float* __restrict__ in, bf16_t* __restrict__ out, int R, int C) {
  __shared__ bf16_t tile[32][33];
  const int bc = blockIdx.x * 32, br = blockIdx.y * 32;
  const int tx = threadIdx.x, ty = threadIdx.y;  // (32, 8)
#pragma unroll
  for (int i = 0; i < 32; i += 8)
    tile[ty + i][tx] = (bf16_t)in[(size_t)(br + ty + i) * C + bc + tx];
  __syncthreads();
#pragma unroll
  for (int i = 0; i < 32; i += 8)
    out[(size_t)(bc + ty + i) * R + br + tx] = tile[tx][ty + i];
}

// ---------------------------------------------------------------------------
// GEMM: C[M][N] = A[M][K] @ B[K][N], with Bt given as B^T row-major [N][K].
// 128x128 tile, BK=32, 256 threads = 4 waves (2x2), each wave 64x64 (4x4 frags).
// EPI==0: f32 store to Cout (row stride N) -- final output.
// EPI==1: QKV split epilogue (bf16): cols <4096 -> qk buffer [M][4096];
//         cols >=4096 (V) -> transposed store vt[(b*8+h)*256+d][2048] at token.
// ---------------------------------------------------------------------------
template <int EPI>
__global__ __launch_bounds__(256) void gemm_bt(
    const bf16_t* __restrict__ A, const bf16_t* __restrict__ Bt,
    void* __restrict__ Cout, bf16_t* __restrict__ Vt, int M, int N, int K) {
  __shared__ __align__(16) bf16_t As[128 * 32];
  __shared__ __align__(16) bf16_t Bs[128 * 32];
  const int tid = threadIdx.x;
  const int lane = tid & 63, w = tid >> 6;
  const int wm = w >> 1, wn = w & 1;
  const int bm = blockIdx.y * 128, bn = blockIdx.x * 128;
  const int l15 = lane & 15, l4 = lane >> 4;

  f32x4 acc[4][4] = {};

  for (int k0 = 0; k0 < K; k0 += 32) {
    __syncthreads();
#pragma unroll
    for (int i = 0; i < 2; ++i) {
      const int idx = i * 256 + tid;
      const int r = idx >> 2, s = idx & 3;
      const int ss = s ^ (r & 3);  // pre-swizzled source seg (XOR involution)
      gload_lds16(A + (size_t)(bm + r) * K + k0 + ss * 8, &As[idx * 8]);
      gload_lds16(Bt + (size_t)(bn + r) * K + k0 + ss * 8, &Bs[idx * 8]);
    }
    __syncthreads();
    bf16x8 af[4], bfr[4];
#pragma unroll
    for (int f = 0; f < 4; ++f) {
      const int ra = wm * 64 + f * 16 + l15;
      const int rb = wn * 64 + f * 16 + l15;
      af[f]  = *(const bf16x8*)&As[ra * 32 + (l4 ^ (ra & 3)) * 8];
      bfr[f] = *(const bf16x8*)&Bs[rb * 32 + (l4 ^ (rb & 3)) * 8];
    }
#pragma unroll
    for (int i = 0; i < 4; ++i)
#pragma unroll
      for (int j = 0; j < 4; ++j) acc[i][j] = MFMA16(af[i], bfr[j], acc[i][j]);
  }

#pragma unroll
  for (int i = 0; i < 4; ++i) {
    const int gr = bm + wm * 64 + i * 16 + l4 * 4;  // 4 consecutive rows gr..gr+3
#pragma unroll
    for (int j = 0; j < 4; ++j) {
      const int gc = bn + wn * 64 + j * 16 + l15;
      if constexpr (EPI == 0) {
        float* C = (float*)Cout;
#pragma unroll
        for (int r = 0; r < 4; ++r)
          C[(size_t)(gr + r) * N + gc] = acc[i][j][r];
      } else {
        bf16_t* C = (bf16_t*)Cout;
        if (gc < 4096) {  // Q or K region: row-major [M][4096]
#pragma unroll
          for (int r = 0; r < 4; ++r)
            C[(size_t)(gr + r) * 4096 + gc] = (bf16_t)acc[i][j][r];
        } else {  // V region: write transposed vt[(b*8+h)*256+d][2048]
          const int c = gc - 4096, h = c >> 8, d = c & 255;
          const int b = gr >> 11, lt = gr & 2047;
          bf16x4 pk;
#pragma unroll
          for (int r = 0; r < 4; ++r) pk[r] = (bf16_t)acc[i][j][r];
          *(bf16x4*)&Vt[((size_t)(b * 8 + h) * 256 + d) * 2048 + lt] = pk;
        }
      }
    }
  }
}

// ---------------------------------------------------------------------------
// Flash attention. Grid: (L/64, B*H). Block 256 = 4 waves; wave w owns q rows
// [qb*64 + w*16, +16), full d=256. K tile [64][256] and V^T tile [256][64] in
// LDS (XOR-swizzled content via pre-swizzled global_load_lds source).
// Online softmax per q-row; P (bf16) roundtrips through per-wave LDS.
// ---------------------------------------------------------------------------
__global__ __launch_bounds__(256) void attn_fwd(
    const bf16_t* __restrict__ qk, const bf16_t* __restrict__ vt,
    bf16_t* __restrict__ ao) {
  __shared__ __align__(16) bf16_t Ks[64 * 256];   // 32KB, keys x d (swizzled)
  __shared__ __align__(16) bf16_t Vs[256 * 64];   // 32KB, d x keys (swizzled)
  __shared__ __align__(16) bf16_t Ps[4 * 16 * 64];// 8KB, per-wave P
  const int tid = threadIdx.x, lane = tid & 63, w = tid >> 6;
  const int l15 = lane & 15, l4 = lane >> 4;
  const int qb = blockIdx.x;        // q tile (64 rows)
  const int bh = blockIdx.y;        // b*8 + h
  const int b = bh >> 3, h = bh & 7;
  const float scale = 0.0625f;      // 1/sqrt(256)

  // Q fragments in registers: row = l15, k-dim = d
  bf16x8 qf[8];
  const bf16_t* qbase =
      qk + (size_t)(b * 2048 + qb * 64 + w * 16 + l15) * 4096 + h * 256 + l4 * 8;
#pragma unroll
  for (int kk = 0; kk < 8; ++kk) qf[kk] = *(const bf16x8*)(qbase + kk * 32);

  f32x4 o[16] = {};
  float m[4] = {-1e30f, -1e30f, -1e30f, -1e30f};
  float lsum[4] = {0.f, 0.f, 0.f, 0.f};

  const bf16_t* kg = qk + (size_t)(b * 2048) * 4096 + 2048 + h * 256;
  const bf16_t* vg = vt + (size_t)bh * 256 * 2048;

  for (int kv = 0; kv < 32; ++kv) {
    __syncthreads();
#pragma unroll
    for (int i = 0; i < 8; ++i) {
      const int idx = i * 256 + tid;
      {  // K tile: row r (key), 32 segs of 8 bf16
        const int r = idx >> 5, s = idx & 31;
        gload_lds16(kg + (size_t)(kv * 64 + r) * 4096 + ((s ^ (r & 7)) * 8),
                    &Ks[idx * 8]);
      }
      {  // V^T tile: row d, 8 segs of 8 keys
        const int d = idx >> 3, s = idx & 7;
        gload_lds16(vg + (size_t)d * 2048 + kv * 64 + ((s ^ (d & 7)) * 8),
                    &Vs[idx * 8]);
      }
    }
    __syncthreads();

    // S = Q @ K^T  (16 q x 64 keys per wave)
    f32x4 s4[4] = {};
#pragma unroll
    for (int kk = 0; kk < 8; ++kk) {
#pragma unroll
      for (int fn = 0; fn < 4; ++fn) {
        const int r = fn * 16 + l15;                 // key row
        const int seg = (kk * 4 + l4) ^ (r & 7);     // swizzled d-seg
        bf16x8 kf = *(const bf16x8*)&Ks[r * 256 + seg * 8];
        s4[fn] = MFMA16(qf[kk], kf, s4[fn]);
      }
    }

    // online softmax (rows l4*4+r; reduce over lanes within 16-group)
    float al[4];
#pragma unroll
    for (int r = 0; r < 4; ++r) {
      float v = fmaxf(fmaxf(s4[0][r], s4[1][r]), fmaxf(s4[2][r], s4[3][r]));
#pragma unroll
      for (int msk = 1; msk < 16; msk <<= 1) v = fmaxf(v, __shfl_xor(v, msk));
      const float mn = fmaxf(m[r], v * scale);
      al[r] = __expf(m[r] - mn);
      m[r] = mn;
    }
    float rs[4] = {0.f, 0.f, 0.f, 0.f};
#pragma unroll
    for (int fn = 0; fn < 4; ++fn) {
#pragma unroll
      for (int r = 0; r < 4; ++r) {
        const float p = __expf(s4[fn][r] * scale - m[r]);
        rs[r] += p;
        const int row = l4 * 4 + r;
        const int col = fn * 16 + l15;
        const int seg = (col >> 3) ^ (row & 7);
        Ps[w * 1024 + row * 64 + seg * 8 + (col & 7)] = (bf16_t)p;
      }
    }
#pragma unroll
    for (int r = 0; r < 4; ++r) {
#pragma unroll
      for (int msk = 1; msk < 16; msk <<= 1) rs[r] += __shfl_xor(rs[r], msk);
      lsum[r] = lsum[r] * al[r] + rs[r];
    }
#pragma unroll
    for (int fd = 0; fd < 16; ++fd)
#pragma unroll
      for (int r = 0; r < 4; ++r) o[fd][r] *= al[r];

    asm volatile("s_waitcnt lgkmcnt(0)" ::: "memory");  // P writes visible wave-wide

    // O += P @ V   (A = P[16 q][64 k], B = V[64 k][256 d] via V^T tile)
#pragma unroll
    for (int ks = 0; ks < 2; ++ks) {
      const int pseg = (ks * 4 + l4) ^ (l15 & 7);
      bf16x8 pa = *(const bf16x8*)&Ps[w * 1024 + l15 * 64 + pseg * 8];
#pragma unroll
      for (int fd = 0; fd < 16; ++fd) {
        const int d = fd * 16 + l15;
        const int seg = (ks * 4 + l4) ^ (d & 7);
        bf16x8 vf = *(const bf16x8*)&Vs[d * 64 + seg * 8];
        o[fd] = MFMA16(pa, vf, o[fd]);
      }
    }
  }

  // epilogue: normalize and store [B*L][2048]
#pragma unroll
  for (int r = 0; r < 4; ++r) {
    const float inv = 1.0f / lsum[r];
    const int row = qb * 64 + w * 16 + l4 * 4 + r;
#pragma unroll
    for (int fd = 0; fd < 16; ++fd) {
      const int col = h * 256 + fd * 16 + l15;
      ao[(size_t)(b * 2048 + row) * 2048 + col] = (bf16_t)(o[fd][r] * inv);
    }
  }
}

// ---------------------------------------------------------------------------
extern "C" void kernel_launch(void* const* d_in, const int* in_sizes, int n_in,
                              void* d_out, int out_size, void* d_ws,
                              size_t ws_size, hipStream_t stream) {
  (void)in_sizes; (void)n_in; (void)out_size; (void)ws_size;
  const float* x    = (const float*)d_in[0];  // [8192][256] f32
  const float* wqkv = (const float*)d_in[1];  // [256][6144] f32
  const float* wout = (const float*)d_in[2];  // [2048][256] f32
  float* out = (float*)d_out;                 // [8192][256] f32

  char* ws = (char*)d_ws;
  bf16_t* xb  = (bf16_t*)(ws);                            // [8192][256]   4.2MB
  bf16_t* wqt = (bf16_t*)(ws + 4194304);                  // [6144][256]   3.1MB
  bf16_t* wot = (bf16_t*)(ws + 7340032);                  // [256][2048]   1.0MB
  bf16_t* qkb = (bf16_t*)(ws + 8388608);                  // [8192][4096]  67MB
  bf16_t* vtb = (bf16_t*)(ws + 8388608 + 67108864);       // [32][256][2048] 33.6MB
  bf16_t* aob = (bf16_t*)(ws + 8388608 + 67108864 + 33554432);  // [8192][2048] 33.6MB

  cvt_f32_bf16<<<2048, 256, 0, stream>>>(x, xb, 8192 * 256);
  transpose_f32_bf16<<<dim3(192, 8), dim3(32, 8), 0, stream>>>(wqkv, wqt, 256, 6144);
  transpose_f32_bf16<<<dim3(8, 64), dim3(32, 8), 0, stream>>>(wout, wot, 2048, 256);
  // qkv = x @ W_qkv, split epilogue (Q,K row-major bf16; V transposed bf16)
  gemm_bt<1><<<dim3(48, 64), 256, 0, stream>>>(xb, wqt, qkb, vtb, 8192, 6144, 256);
  // attention
  attn_fwd<<<dim3(32, 32), 256, 0, stream>>>(qkb, vtb, aob);
  // out = attn_out @ W_out (f32 store)
  gemm_bt<0><<<dim3(2, 64), 256, 0, stream>>>(aob, wot, out, nullptr, 8192, 256, 2048);
}

// Round 3
// 295.932 us; speedup vs baseline: 1.6339x; 1.6339x over previous
//
#include <hip/hip_runtime.h>
#include <cstdint>
#include <cstddef>

typedef __bf16 bf16_t;
typedef __bf16 bf16x8 __attribute__((ext_vector_type(8)));
typedef __bf16 bf16x4 __attribute__((ext_vector_type(4)));
typedef float  f32x4  __attribute__((ext_vector_type(4)));
typedef int    i32x4  __attribute__((ext_vector_type(4)));

#define MFMA16(a, b, c) __builtin_amdgcn_mfma_f32_16x16x32_bf16((a), (b), (c), 0, 0, 0)

// async global->LDS, 16B per lane. LDS dest must be wave-linear (base + lane*16).
__device__ __forceinline__ void gload_lds16(const bf16_t* g, bf16_t* l) {
  __builtin_amdgcn_global_load_lds(
      (__attribute__((address_space(1))) void*)((void*)g),
      (__attribute__((address_space(3))) void*)l, 16, 0, 0);
}

// ---------------------------------------------------------------------------
// x convert: f32 -> bf16, 4 elems/thread.
// ---------------------------------------------------------------------------
__global__ __launch_bounds__(256) void cvt_f32_bf16(
    const float* __restrict__ in, bf16_t* __restrict__ out, int n) {
  const int i = (blockIdx.x * 256 + threadIdx.x) * 4;
  if (i + 3 < n) {
    const float4 v = *(const float4*)(in + i);
    bf16x4 o;
    o[0] = (bf16_t)v.x; o[1] = (bf16_t)v.y; o[2] = (bf16_t)v.z; o[3] = (bf16_t)v.w;
    *(bf16x4*)(out + i) = o;
  }
}

// ---------------------------------------------------------------------------
// Weight transpose+convert: in f32 [R][C] -> out bf16 [C][R]; R,C mult of 32.
// ---------------------------------------------------------------------------
__global__ __launch_bounds__(256) void transpose_f32_bf16(
    const float* __restrict__ in, bf16_t* __restrict__ out, int R, int C) {
  __shared__ bf16_t tile[32][33];
  const int bc = blockIdx.x * 32, br = blockIdx.y * 32;
  const int tx = threadIdx.x, ty = threadIdx.y;  // (32, 8)
#pragma unroll
  for (int i = 0; i < 32; i += 8)
    tile[ty + i][tx] = (bf16_t)in[(size_t)(br + ty + i) * C + bc + tx];
  __syncthreads();
#pragma unroll
  for (int i = 0; i < 32; i += 8)
    out[(size_t)(bc + ty + i) * R + br + tx] = tile[tx][ty + i];
}

// ---------------------------------------------------------------------------
// GEMM: C[M][N] = A[M][K] @ B[K][N], with Bt given as B^T row-major [N][K].
// 128x128 tile, BK=32, 256 threads = 4 waves (2x2), each wave 64x64 (4x4 frags).
// EPI==0: f32 store to Cout (row stride N) -- final output.
// EPI==1: QKV split epilogue (bf16): cols <4096 -> qk buffer [M][4096];
//         cols >=4096 (V) -> transposed store vt[(b*8+h)*256+d][2048] at token.
// ---------------------------------------------------------------------------
template <int EPI>
__global__ __launch_bounds__(256) void gemm_bt(
    const bf16_t* __restrict__ A, const bf16_t* __restrict__ Bt,
    void* __restrict__ Cout, bf16_t* __restrict__ Vt, int M, int N, int K) {
  __shared__ __align__(16) bf16_t As[128 * 32];
  __shared__ __align__(16) bf16_t Bs[128 * 32];
  const int tid = threadIdx.x;
  const int lane = tid & 63, w = tid >> 6;
  const int wm = w >> 1, wn = w & 1;
  const int bm = blockIdx.y * 128, bn = blockIdx.x * 128;
  const int l15 = lane & 15, l4 = lane >> 4;

  f32x4 acc[4][4] = {};

  for (int k0 = 0; k0 < K; k0 += 32) {
    __syncthreads();
#pragma unroll
    for (int i = 0; i < 2; ++i) {
      const int idx = i * 256 + tid;
      const int r = idx >> 2, s = idx & 3;
      const int ss = s ^ (r & 3);  // pre-swizzled source seg (XOR involution)
      gload_lds16(A + (size_t)(bm + r) * K + k0 + ss * 8, &As[idx * 8]);
      gload_lds16(Bt + (size_t)(bn + r) * K + k0 + ss * 8, &Bs[idx * 8]);
    }
    __syncthreads();
    bf16x8 af[4], bfr[4];
#pragma unroll
    for (int f = 0; f < 4; ++f) {
      const int ra = wm * 64 + f * 16 + l15;
      const int rb = wn * 64 + f * 16 + l15;
      af[f]  = *(const bf16x8*)&As[ra * 32 + (l4 ^ (ra & 3)) * 8];
      bfr[f] = *(const bf16x8*)&Bs[rb * 32 + (l4 ^ (rb & 3)) * 8];
    }
#pragma unroll
    for (int i = 0; i < 4; ++i)
#pragma unroll
      for (int j = 0; j < 4; ++j) acc[i][j] = MFMA16(af[i], bfr[j], acc[i][j]);
  }

#pragma unroll
  for (int i = 0; i < 4; ++i) {
    const int gr = bm + wm * 64 + i * 16 + l4 * 4;  // 4 consecutive rows gr..gr+3
#pragma unroll
    for (int j = 0; j < 4; ++j) {
      const int gc = bn + wn * 64 + j * 16 + l15;
      if constexpr (EPI == 0) {
        float* C = (float*)Cout;
#pragma unroll
        for (int r = 0; r < 4; ++r)
          C[(size_t)(gr + r) * N + gc] = acc[i][j][r];
      } else {
        bf16_t* C = (bf16_t*)Cout;
        if (gc < 4096) {  // Q or K region: row-major [M][4096]
#pragma unroll
          for (int r = 0; r < 4; ++r)
            C[(size_t)(gr + r) * 4096 + gc] = (bf16_t)acc[i][j][r];
        } else {  // V region: write transposed vt[(b*8+h)*256+d][2048]
          const int c = gc - 4096, h = c >> 8, d = c & 255;
          const int b = gr >> 11, lt = gr & 2047;
          bf16x4 pk;
#pragma unroll
          for (int r = 0; r < 4; ++r) pk[r] = (bf16_t)acc[i][j][r];
          *(bf16x4*)&Vt[((size_t)(b * 8 + h) * 256 + d) * 2048 + lt] = pk;
        }
      }
    }
  }
}

// ---------------------------------------------------------------------------
// Flash attention, swapped-QK^T + reg-staged prefetch.
// Grid: 512 blocks (XCD-swizzled). Block 512 = 8 waves; block owns 128 q rows
// (wave w: rows qb*128 + w*16 + l15), full d=256, over B*H=32 (b,h) pairs.
// Per kv iter (64 keys): S^T = mfma(K,Q) -> per-lane scalar online softmax ->
// P via padded wave-private LDS (conflict-free) -> O^T += mfma(V^T, P).
// K tile [64][256] and V^T tile [256][64] XOR-swizzled in LDS; next tile
// loaded global->reg during compute (T14), ds_write after barrier.
// ---------------------------------------------------------------------------
__global__ __launch_bounds__(512, 2) void attn_fwd(
    const bf16_t* __restrict__ qk, const bf16_t* __restrict__ vt,
    bf16_t* __restrict__ ao) {
  __shared__ __align__(16) bf16_t Ks[64 * 256];      // 32KB
  __shared__ __align__(16) bf16_t Vs[256 * 64];      // 32KB
  __shared__ __align__(16) bf16_t Ps[8][16 * 72];    // 18KB, stride-72 pad
  const int tid = threadIdx.x, lane = tid & 63, w = tid >> 6;
  const int l15 = lane & 15, l4 = lane >> 4;
  // XCD-aware swizzle: 512 blocks % 8 == 0, chunk 64 -> 4 bh per XCD
  const int bid = blockIdx.x;
  const int swz = (bid & 7) * 64 + (bid >> 3);
  const int qb = swz & 15;          // 16 q-tiles of 128 rows
  const int bh = swz >> 4;          // 32 (b,h) pairs
  const int b = bh >> 3, h = bh & 7;
  const float scale = 0.0625f;      // 1/sqrt(256)

  // Q fragments: lane holds Q[q=l15][d = kk*32 + l4*8 ..+7]
  const int qrow = qb * 128 + w * 16 + l15;
  const bf16_t* qbase =
      qk + (size_t)(b * 2048 + qrow) * 4096 + h * 256 + l4 * 8;
  bf16x8 qf[8];
#pragma unroll
  for (int kk = 0; kk < 8; ++kk) qf[kk] = *(const bf16x8*)(qbase + kk * 32);

  const bf16_t* kg = qk + (size_t)(b * 2048) * 4096 + 2048 + h * 256;
  const bf16_t* vg = vt + (size_t)bh * 256 * 2048;

  // staging decomposition: 512 threads x 4 chunks x 16B = 32KB per tile
  int krow[4], kseg[4], vrow[4], vseg[4];
#pragma unroll
  for (int i = 0; i < 4; ++i) {
    const int idx = i * 512 + tid;
    krow[i] = idx >> 5; kseg[i] = idx & 31;   // K: [64 rows][32 segs]
    vrow[i] = idx >> 3; vseg[i] = idx & 7;    // V^T: [256 rows][8 segs]
  }

  i32x4 stK[4], stV[4];
#pragma unroll
  for (int i = 0; i < 4; ++i) {  // prologue: tile kv=0 -> regs
    stK[i] = *(const i32x4*)(kg + (size_t)krow[i] * 4096 + kseg[i] * 8);
    stV[i] = *(const i32x4*)(vg + (size_t)vrow[i] * 2048 + vseg[i] * 8);
  }

  f32x4 o[16] = {};
  float m = -1e30f, lsum = 0.f;

  for (int kv = 0; kv < 32; ++kv) {
    __syncthreads();  // all waves done reading LDS from previous iter
#pragma unroll
    for (int i = 0; i < 4; ++i) {  // regs -> LDS, XOR-swizzled
      *(i32x4*)&Ks[(krow[i] * 32 + (kseg[i] ^ (krow[i] & 7))) * 8] = stK[i];
      *(i32x4*)&Vs[(vrow[i] * 8 + (vseg[i] ^ (vrow[i] & 7))) * 8] = stV[i];
    }
    __syncthreads();  // tiles ready
    // issue next tile's global loads now; they fly under the compute below
    const int nx = (kv + 1 < 32) ? kv + 1 : kv;
#pragma unroll
    for (int i = 0; i < 4; ++i) {
      stK[i] = *(const i32x4*)(kg + (size_t)(nx * 64 + krow[i]) * 4096 + kseg[i] * 8);
      stV[i] = *(const i32x4*)(vg + (size_t)vrow[i] * 2048 + nx * 64 + vseg[i] * 8);
    }

    // S^T[key][q] = mfma(K, Q): out row = key (l4*4+reg within fn*16), col = q = l15
    f32x4 s4[4] = {};
    __builtin_amdgcn_s_setprio(1);
#pragma unroll
    for (int kk = 0; kk < 8; ++kk) {
#pragma unroll
      for (int fn = 0; fn < 4; ++fn) {
        bf16x8 kf = *(const bf16x8*)
            &Ks[((fn * 16 + l15) * 32 + ((kk * 4 + l4) ^ (l15 & 7))) * 8];
        s4[fn] = MFMA16(kf, qf[kk], s4[fn]);
      }
    }
    __builtin_amdgcn_s_setprio(0);

    // per-lane scalar online softmax (q = l15; 4 l4-lanes share q)
    float v = s4[0][0];
#pragma unroll
    for (int fn = 0; fn < 4; ++fn)
#pragma unroll
      for (int r = 0; r < 4; ++r) v = fmaxf(v, s4[fn][r]);
    v = fmaxf(v, __shfl_xor(v, 16));
    v = fmaxf(v, __shfl_xor(v, 32));
    const float mn = fmaxf(m, v * scale);
    const float al = __expf(m - mn);
    m = mn;

    float rs = 0.f;
#pragma unroll
    for (int fn = 0; fn < 4; ++fn) {
      bf16x4 pw;
#pragma unroll
      for (int r = 0; r < 4; ++r) {
        const float p = __expf(s4[fn][r] * scale - mn);
        rs += p;
        pw[r] = (bf16_t)p;
      }
      // Ps[q][key]: q=l15 (stride 72), keys fn*16 + l4*4 .. +3 (8B store)
      *(bf16x4*)&Ps[w][l15 * 72 + fn * 16 + l4 * 4] = pw;
    }
    rs += __shfl_xor(rs, 16);
    rs += __shfl_xor(rs, 32);
    lsum = lsum * al + rs;
#pragma unroll
    for (int fd = 0; fd < 16; ++fd) {
      o[fd][0] *= al; o[fd][1] *= al; o[fd][2] *= al; o[fd][3] *= al;
    }

    // O^T[d][q] += mfma(V^T, P): A = V^T rows d, B^T = P rows q
    bf16x8 pb[2];
#pragma unroll
    for (int ks = 0; ks < 2; ++ks)
      pb[ks] = *(const bf16x8*)&Ps[w][l15 * 72 + ks * 32 + l4 * 8];
    __builtin_amdgcn_s_setprio(1);
#pragma unroll
    for (int ks = 0; ks < 2; ++ks) {
#pragma unroll
      for (int fd = 0; fd < 16; ++fd) {
        bf16x8 vf = *(const bf16x8*)
            &Vs[((fd * 16 + l15) * 8 + ((ks * 4 + l4) ^ (l15 & 7))) * 8];
        o[fd] = MFMA16(vf, pb[ks], o[fd]);
      }
    }
    __builtin_amdgcn_s_setprio(0);
  }

  // epilogue: normalize, store O^T frags to ao[token][h*256+d]
  const float inv = 1.0f / lsum;
#pragma unroll
  for (int fd = 0; fd < 16; ++fd) {
    bf16x4 ov;
#pragma unroll
    for (int r = 0; r < 4; ++r) ov[r] = (bf16_t)(o[fd][r] * inv);
    *(bf16x4*)&ao[(size_t)(b * 2048 + qrow) * 2048 + h * 256 + fd * 16 + l4 * 4] = ov;
  }
}

// ---------------------------------------------------------------------------
extern "C" void kernel_launch(void* const* d_in, const int* in_sizes, int n_in,
                              void* d_out, int out_size, void* d_ws,
                              size_t ws_size, hipStream_t stream) {
  (void)in_sizes; (void)n_in; (void)out_size; (void)ws_size;
  const float* x    = (const float*)d_in[0];  // [8192][256] f32
  const float* wqkv = (const float*)d_in[1];  // [256][6144] f32
  const float* wout = (const float*)d_in[2];  // [2048][256] f32
  float* out = (float*)d_out;                 // [8192][256] f32

  char* ws = (char*)d_ws;
  bf16_t* xb  = (bf16_t*)(ws);                            // [8192][256]   4.2MB
  bf16_t* wqt = (bf16_t*)(ws + 4194304);                  // [6144][256]   3.1MB
  bf16_t* wot = (bf16_t*)(ws + 7340032);                  // [256][2048]   1.0MB
  bf16_t* qkb = (bf16_t*)(ws + 8388608);                  // [8192][4096]  67MB
  bf16_t* vtb = (bf16_t*)(ws + 8388608 + 67108864);       // [32][256][2048] 33.6MB
  bf16_t* aob = (bf16_t*)(ws + 8388608 + 67108864 + 33554432);  // [8192][2048] 33.6MB

  cvt_f32_bf16<<<2048, 256, 0, stream>>>(x, xb, 8192 * 256);
  transpose_f32_bf16<<<dim3(192, 8), dim3(32, 8), 0, stream>>>(wqkv, wqt, 256, 6144);
  transpose_f32_bf16<<<dim3(8, 64), dim3(32, 8), 0, stream>>>(wout, wot, 2048, 256);
  // qkv = x @ W_qkv, split epilogue (Q,K row-major bf16; V transposed bf16)
  gemm_bt<1><<<dim3(48, 64), 256, 0, stream>>>(xb, wqt, qkb, vtb, 8192, 6144, 256);
  // attention
  attn_fwd<<<512, 512, 0, stream>>>(qkb, vtb, aob);
  // out = attn_out @ W_out (f32 store)
  gemm_bt<0><<<dim3(2, 64), 256, 0, stream>>>(aob, wot, out, nullptr, 8192, 256, 2048);
}